// Round 8
// baseline (224.185 us; speedup 1.0000x reference)
//
#include <hip/hip_runtime.h>

#define EPS 1e-9f
constexpr int NN = 131072;
constexpr int CD = 64;
constexpr int KK = 32;
constexpr int BB = 16;

typedef __attribute__((ext_vector_type(8))) short short8;   // 8 bf16 (4 VGPRs)
typedef __attribute__((ext_vector_type(4))) float f32x4;

// ---- workspace layout (float offsets) ----
constexpr int WS_ENT  = 0;                    // entropy accumulator
constexpr int WS_BACC = 16;                   // bacc[B][K][FP]
constexpr int FP      = 72;
constexpr int WS_BACC_SZ = BB * KK * FP;      // 36864
constexpr int WS_W1F  = WS_BACC + WS_BACC_SZ; // 4096 ushort (2048 fl): W1 MFMA frags
constexpr int WS_W2F  = WS_W1F + 2048;        // 2048 ushort (1024 fl): W2 frags (scaled)
constexpr int WS_B2F  = WS_W2F + 1024;        // 32 fl: b2*sc with mask folded
constexpr int WS_TAG  = WS_B2F + 32;          // 1024 int tags
constexpr int WS_PART = 41024;                // per-block partials [nblk][2176], cell = k*68+f
constexpr int CELLS   = 68 * 32;

// ---- output layout (float offsets) ----
constexpr int OUT_OUT  = 0;                   // [B,K,C]
constexpr int OUT_S    = BB * KK * CD;        // s [N,K]
constexpr int OUT_SCAL = OUT_S + NN * KK;     // 6 scalars
constexpr int OUT_MU   = OUT_SCAL + 6;        // mu [B,K,2]

__device__ __forceinline__ unsigned short f2bf(float f) {   // RNE float->bf16
    unsigned b = __builtin_bit_cast(unsigned, f);
    b += 0x7fffu + ((b >> 16) & 1u);
    return (unsigned short)(b >> 16);
}

// Pre-pack W1/W2 into per-lane MFMA fragment order; fold scaling+mask into W2/b2.
__global__ void prep_k(const float* __restrict__ W1, const float* __restrict__ W2,
                       const float* __restrict__ b2, const float* __restrict__ scaling,
                       const float* __restrict__ amask, float* __restrict__ ws) {
    const int t = threadIdx.x;
    const float sc = scaling[0];
    unsigned short* w1f = (unsigned short*)(ws + WS_W1F);
    for (int idx = t; idx < 4096; idx += 256) {
        int e = idx & 7, lane = (idx >> 3) & 63, f = idx >> 9;
        int nt = f >> 1, ks = f & 1;
        int j = nt * 16 + (lane & 15);
        int c = ks * 32 + (lane >> 4) * 8 + e;
        w1f[idx] = f2bf(W1[c * 64 + j]);
    }
    unsigned short* w2f = (unsigned short*)(ws + WS_W2F);
    for (int idx = t; idx < 2048; idx += 256) {
        int e = idx & 7, lane = (idx >> 3) & 63, f = idx >> 9;
        int nt = f >> 1, ks = f & 1;
        int j = nt * 16 + (lane & 15);
        int c = ks * 32 + (lane >> 4) * 8 + e;
        w2f[idx] = f2bf(sc * W2[c * 32 + j]);
    }
    if (t < 32) ws[WS_B2F + t] = (amask[t] == 0.f) ? -1e9f : b2[t] * sc;
}

// MFMA node kernel (unchanged from round 7: passed, absmax 0.25)
__global__ __launch_bounds__(256)
void node_k(const float* __restrict__ x, const float* __restrict__ u,
            const float* __restrict__ b1, const float* __restrict__ ws,
            float* __restrict__ s_out, float* __restrict__ ent_acc) {
    __shared__ unsigned short Hlds[4096];
    __shared__ float Llds[64 * 33];
    __shared__ float entred[4];
    const int t = threadIdx.x;
    const int w = t >> 6, l = t & 63, lj = l & 15, lg = l >> 4;
    const unsigned short* w1f = (const unsigned short*)(ws + WS_W1F);
    const unsigned short* w2f = (const unsigned short*)(ws + WS_W2F);
    const float* b2f = ws + WS_B2F;

    const int node = blockIdx.x * 64 + w * 16 + lj;
    const float* xr = x + (size_t)node * 64 + lg * 8;
    short8 a0, a1;
    {
        float4 p0 = *(const float4*)xr;
        float4 p1 = *(const float4*)(xr + 4);
        float4 p2 = *(const float4*)(xr + 32);
        float4 p3 = *(const float4*)(xr + 36);
        a0[0] = f2bf(p0.x); a0[1] = f2bf(p0.y); a0[2] = f2bf(p0.z); a0[3] = f2bf(p0.w);
        a0[4] = f2bf(p1.x); a0[5] = f2bf(p1.y); a0[6] = f2bf(p1.z); a0[7] = f2bf(p1.w);
        a1[0] = f2bf(p2.x); a1[1] = f2bf(p2.y); a1[2] = f2bf(p2.z); a1[3] = f2bf(p2.w);
        a1[4] = f2bf(p3.x); a1[5] = f2bf(p3.y); a1[6] = f2bf(p3.z); a1[7] = f2bf(p3.w);
    }
    f32x4 hacc[4];
#pragma unroll
    for (int nt = 0; nt < 4; nt++) {
        f32x4 acc = {0.f, 0.f, 0.f, 0.f};
        short8 b0 = *(const short8*)(w1f + (nt * 2 + 0) * 512 + l * 8);
        short8 b1v = *(const short8*)(w1f + (nt * 2 + 1) * 512 + l * 8);
        acc = __builtin_amdgcn_mfma_f32_16x16x32_bf16(a0, b0, acc, 0, 0, 0);
        acc = __builtin_amdgcn_mfma_f32_16x16x32_bf16(a1, b1v, acc, 0, 0, 0);
        hacc[nt] = acc;
    }
#pragma unroll
    for (int nt = 0; nt < 4; nt++) {
        const float bias = b1[nt * 16 + lj];
#pragma unroll
        for (int q = 0; q < 4; q++) {
            const int r = lg * 4 + q;
            const float hv = fmaxf(hacc[nt][q] + bias, 0.f);
            const int bo = (nt * 32 + lj * 2) ^ ((r & 7) << 4);
            Hlds[w * 1024 + r * 64 + (bo >> 1)] = f2bf(hv);
        }
    }
    short8 a20, a21;
    {
        const int base = w * 1024 + lj * 64;
        a20 = *(const short8*)(Hlds + base + ((lg ^ (lj & 7)) << 3));
        a21 = *(const short8*)(Hlds + base + (((4 + lg) ^ (lj & 7)) << 3));
    }
#pragma unroll
    for (int nt = 0; nt < 2; nt++) {
        f32x4 acc = {0.f, 0.f, 0.f, 0.f};
        short8 b0 = *(const short8*)(w2f + (nt * 2 + 0) * 512 + l * 8);
        short8 b1v = *(const short8*)(w2f + (nt * 2 + 1) * 512 + l * 8);
        acc = __builtin_amdgcn_mfma_f32_16x16x32_bf16(a20, b0, acc, 0, 0, 0);
        acc = __builtin_amdgcn_mfma_f32_16x16x32_bf16(a21, b1v, acc, 0, 0, 0);
        const float bb = b2f[nt * 16 + lj];
#pragma unroll
        for (int q = 0; q < 4; q++)
            Llds[(w * 16 + lg * 4 + q) * 33 + nt * 16 + lj] = acc[q] + bb;
    }
    __syncthreads();

    const int nl = t >> 2, sub = t & 3;
    const int n = blockIdx.x * 64 + nl;
    const float* Lr = &Llds[nl * 33 + sub * 8];
    const float* ur = u + (size_t)n * 32 + sub * 8;
    float4 u0 = *(const float4*)ur, u1 = *(const float4*)(ur + 4);
    float uu[8] = {u0.x, u0.y, u0.z, u0.w, u1.x, u1.y, u1.z, u1.w};
    float z[8];
    float m = -3.0e38f;
#pragma unroll
    for (int i = 0; i < 8; i++) {
        float g = -__logf(-__logf(uu[i] + EPS) + EPS);
        z[i] = Lr[i] + g;
        m = fmaxf(m, z[i]);
    }
    m = fmaxf(m, __shfl_xor(m, 1, 64));
    m = fmaxf(m, __shfl_xor(m, 2, 64));
    float es = 0.f;
#pragma unroll
    for (int i = 0; i < 8; i++) { z[i] = __expf(z[i] - m); es += z[i]; }
    es += __shfl_xor(es, 1, 64);
    es += __shfl_xor(es, 2, 64);
    const float inv = 1.f / es;
    float ent = 0.f;
#pragma unroll
    for (int i = 0; i < 8; i++) {
        float sv = z[i] * inv;
        z[i] = sv;
        ent += sv * __logf(sv + EPS);
    }
    float* so = s_out + (size_t)n * 32 + sub * 8;
    *(float4*)so = make_float4(z[0], z[1], z[2], z[3]);
    *(float4*)(so + 4) = make_float4(z[4], z[5], z[6], z[7]);
#pragma unroll
    for (int off = 32; off > 0; off >>= 1) ent += __shfl_down(ent, off, 64);
    if (l == 0) entred[w] = ent;
    __syncthreads();
    if (t == 0) atomicAdd(ent_acc, entred[0] + entred[1] + entred[2] + entred[3]);
}

// Pool, restructured: lane = feature f (x[n][l] coalesced dword), wave = 32-node
// sub-range, k carried in 32 registers. s[n][0..31] and pos[n] are WAVE-UNIFORM
// addresses -> scalar s_loads (SGPR broadcast), so the inner loop is pure
// v_fmac(acc[kk], s_sgpr, xv): no broadcast-amplified VMEM (round-7: 2KB
// requested per wave-n for 64B of data = the 57us). Per-wave partials merge in
// LDS; boundary flushes (rare) go straight to bacc with atomics.
__global__ __launch_bounds__(256)
void pool_k(const float* __restrict__ s, const float* __restrict__ x,
            const float* __restrict__ pos, const int* __restrict__ batch,
            float* __restrict__ bacc, float* __restrict__ part,
            int* __restrict__ tags, int npb) {
    __shared__ float Plds[CELLS];                 // [k*68+f] fp32
    const int t = threadIdx.x;
    const int l = t & 63;
    const int w = __builtin_amdgcn_readfirstlane(t >> 6);   // wave id, uniform
    for (int idx = t; idx < CELLS; idx += 256) Plds[idx] = 0.f;
    const int base = blockIdx.x * npb;
    const int wn = npb >> 2;
    const int n0 = base + w * wn, n1 = n0 + wn;
    float acc[32];
#pragma unroll
    for (int kk = 0; kk < 32; kk++) acc[kk] = 0.f;
    float a2x = 0.f, a2y = 0.f, a2q = 0.f, a2s = 0.f;   // lanes<32: k=l pos feats
    int cur_b = batch[n0];
    __syncthreads();
#pragma unroll 2
    for (int n = n0; n < n1; n++) {
        const int b = batch[n];                   // uniform scalar load
        if (b != cur_b) {                         // uniform branch, rare
            float* dst = bacc + (cur_b * 32) * FP + l;
#pragma unroll
            for (int kk = 0; kk < 32; kk++) { atomicAdd(dst + kk * FP, acc[kk]); acc[kk] = 0.f; }
            if (l < 32) {
                float* d2 = bacc + (cur_b * 32 + l) * FP + 64;
                atomicAdd(d2 + 0, a2x); atomicAdd(d2 + 1, a2y);
                atomicAdd(d2 + 2, a2q); atomicAdd(d2 + 3, a2s);
                a2x = a2y = a2q = a2s = 0.f;
            }
            cur_b = b;
        }
        const float xv = x[(size_t)n * 64 + l];        // coalesced vector dword
        const float sv = s[(size_t)n * 32 + (l & 31)]; // coalesced vector dword
        const float* sr = s + (size_t)n * 32;          // uniform -> s_load x16
#pragma unroll
        for (int kk = 0; kk < 32; kk++)
            acc[kk] = fmaf(sr[kk], xv, acc[kk]);       // v_fmac v, s, v
        const float* pr = pos + (size_t)n * 2;         // uniform -> s_load x2
        const float px = pr[0], py = pr[1];
        const float tx = sv * px, ty = sv * py;
        a2x += tx; a2y += ty;
        a2q = fmaf(tx, px, fmaf(ty, py, a2q));
        a2s += sv;
    }
    const int tagb = batch[base + npb - 1];            // block tag (uniform)
    if (cur_b == tagb) {
#pragma unroll
        for (int kk = 0; kk < 32; kk++) atomicAdd(&Plds[kk * 68 + l], acc[kk]);
        if (l < 32) {
            atomicAdd(&Plds[l * 68 + 64], a2x);
            atomicAdd(&Plds[l * 68 + 65], a2y);
            atomicAdd(&Plds[l * 68 + 66], a2q);
            atomicAdd(&Plds[l * 68 + 67], a2s);
        }
    } else {                                           // wave ended before tag's segment
        float* dst = bacc + (cur_b * 32) * FP + l;
#pragma unroll
        for (int kk = 0; kk < 32; kk++) atomicAdd(dst + kk * FP, acc[kk]);
        if (l < 32) {
            float* d2 = bacc + (cur_b * 32 + l) * FP + 64;
            atomicAdd(d2 + 0, a2x); atomicAdd(d2 + 1, a2y);
            atomicAdd(d2 + 2, a2q); atomicAdd(d2 + 3, a2s);
        }
    }
    __syncthreads();
    float* pp = part + (size_t)blockIdx.x * CELLS;
    for (int idx = t; idx < CELLS; idx += 256) pp[idx] = Plds[idx];  // coalesced
    if (t == 0) tags[blockIdx.x] = tagb;
}

// per-(b,cell) partial reduce; cell = k*68 + f now.
__global__ void reduce_k(const float* __restrict__ part,
                         const int* __restrict__ tags,
                         float* __restrict__ bacc,
                         float* __restrict__ outp,
                         int nblk) {
    const int b = blockIdx.x;
    const int cell = blockIdx.y * 256 + threadIdx.x;
    if (cell >= CELLS) return;
    const int k = cell / 68, f = cell - k * 68;
    int lo = 0, hi = nblk;
    while (lo < hi) { int mid = (lo + hi) >> 1; if (tags[mid] < b) lo = mid + 1; else hi = mid; }
    int lo2 = lo, hi2 = nblk;
    while (lo2 < hi2) { int mid = (lo2 + hi2) >> 1; if (tags[mid] < b + 1) lo2 = mid + 1; else hi2 = mid; }
    float v = 0.f;
#pragma unroll 4
    for (int blk = lo; blk < lo2; blk++)
        v += part[(size_t)blk * CELLS + cell];
    const int idx = (b * 32 + k) * FP + f;
    const float tot = bacc[idx] + v;
    bacc[idx] = tot;
    if (f < 64) outp[OUT_OUT + ((b * 32 + k) << 6) + f] = tot;
}

// single block: mu + six scalars (unchanged)
__global__ void fin_k(const float* __restrict__ ws,
                      const float* __restrict__ amask,
                      float* __restrict__ outp) {
    const int t = threadIdx.x;
    const float* bacc = ws + WS_BACC;
    __shared__ float mu_s[BB * KK * 2];
    for (int idx = t; idx < BB * KK * 2; idx += 256) {
        int bk = idx >> 1, d = idx & 1;
        float v = bacc[bk * FP + 64 + d] / (bacc[bk * FP + 67] + EPS);
        mu_s[idx] = v;
        outp[OUT_MU + idx] = v;
    }
    __shared__ float kred[32][4];
    if (t < 32) {
        float S = 0, px = 0, py = 0, sq = 0;
        for (int b = 0; b < 16; b++) {
            const float* pp = bacc + (b * 32 + t) * FP;
            S += pp[67]; px += pp[64]; py += pp[65]; sq += pp[66];
        }
        float avg = S / (float)NN;
        float am = amask[t];
        float ssum = S + EPS;
        float mx = px / ssum, my = py / ssum;
        kred[t][0] = avg * __logf(avg + EPS);
        kred[t][1] = fabsf(avg * (1.f - am));
        kred[t][2] = sq / ssum - mx * mx - my * my;
        kred[t][3] = am;
    }
    __syncthreads();
    float sep = 0.f;
    for (int idx = t; idx < BB * KK * KK; idx += 256) {
        int b = idx >> 10, i = (idx >> 5) & 31, j = idx & 31;
        if (i != j) {
            float dx = mu_s[(b * 32 + i) * 2 + 0] - mu_s[(b * 32 + j) * 2 + 0];
            float dy = mu_s[(b * 32 + i) * 2 + 1] - mu_s[(b * 32 + j) * 2 + 1];
            sep += 1.f / (dx * dx + dy * dy + 1.f);
        }
    }
    __shared__ float red[256];
    red[t] = sep;
    __syncthreads();
    for (int s2 = 128; s2 > 0; s2 >>= 1) {
        if (t < s2) red[t] += red[t + s2];
        __syncthreads();
    }
    if (t == 0) {
        float div = 0, pru = 0, spa = 0, spar = 0;
        for (int kq = 0; kq < 32; kq++) {
            div += kred[kq][0]; pru += kred[kq][1];
            spa += kred[kq][2]; spar += kred[kq][3];
        }
        outp[OUT_SCAL + 0] = -ws[WS_ENT] / (float)NN;
        outp[OUT_SCAL + 1] = div;
        outp[OUT_SCAL + 2] = spa / 32.f;
        outp[OUT_SCAL + 3] = pru / 32.f;
        outp[OUT_SCAL + 4] = spar / 32.f;
        outp[OUT_SCAL + 5] = red[0] / (32.f * 31.f + EPS);
    }
}

extern "C" void kernel_launch(void* const* d_in, const int* in_sizes, int n_in,
                              void* d_out, int out_size, void* d_ws, size_t ws_size,
                              hipStream_t stream) {
    const float* x       = (const float*)d_in[0];
    const int*   batch   = (const int*)d_in[1];
    const float* pos     = (const float*)d_in[2];
    const float* u       = (const float*)d_in[3];
    const float* W1      = (const float*)d_in[4];
    const float* b1      = (const float*)d_in[5];
    const float* W2      = (const float*)d_in[6];
    const float* b2      = (const float*)d_in[7];
    const float* scaling = (const float*)d_in[8];
    const float* amask   = (const float*)d_in[9];
    float* outp = (float*)d_out;
    float* ws   = (float*)d_ws;

    int npb = 128;
    while (npb < NN &&
           ws_size < ((size_t)WS_PART + (size_t)(NN / npb) * CELLS) * sizeof(float))
        npb <<= 1;
    const int nblk = NN / npb;

    hipMemsetAsync(ws, 0, (size_t)(WS_BACC + WS_BACC_SZ) * sizeof(float), stream);
    prep_k<<<1, 256, 0, stream>>>(W1, W2, b2, scaling, amask, ws);
    node_k<<<NN / 64, 256, 0, stream>>>(x, u, b1, ws, outp + OUT_S, ws + WS_ENT);
    pool_k<<<nblk, 256, 0, stream>>>(outp + OUT_S, x, pos, batch,
                                     ws + WS_BACC, ws + WS_PART, (int*)(ws + WS_TAG), npb);
    reduce_k<<<dim3(BB, (CELLS + 255) / 256), 256, 0, stream>>>(
        ws + WS_PART, (const int*)(ws + WS_TAG), ws + WS_BACC, outp, nblk);
    fin_k<<<1, 256, 0, stream>>>(ws, amask, outp);
}